// Round 6
// baseline (249.757 us; speedup 1.0000x reference)
//
#include <hip/hip_runtime.h>
#include <math.h>

#define TOKENS 16384
#define HIDDEN 2048
#define NEXP   64
#define MT     32                  // tokens per block
#define NSTEP  (HIDDEN / 32)       // 64 K-steps of 32
#define NBLK   (TOKENS / MT)       // 512

#define GATES_OFF (TOKENS * 2)
#define SEL_OFF   (GATES_OFF + TOKENS * NEXP)
#define Z_OFF     (SEL_OFF + TOKENS * 2)

#define WIMG_BYTES (NEXP * HIDDEN * 2 * 2)   // 512 KB: fp16 wh+wl fragment image

typedef __attribute__((ext_vector_type(8))) _Float16 f16x8;
typedef __attribute__((ext_vector_type(4))) float    f32x4;

__device__ __forceinline__ float wave_sum64(float v) {
    #pragma unroll
    for (int s = 1; s < 64; s <<= 1) v += __shfl_xor(v, s, 64);
    return v;
}

// ---------------------------------------------------------------------------
// Setup: convert w [64,2048] fp32 -> fp16 (hi, lo*4096) fragment image in ws.
// Image: [chunk 32][r 1024] of 16-B slots; r = eh*512 + term*256 + kh*128 +
// nt*64 + lane. Slot lane l: n = l&15, klocal = (l>>4)*8 + j (verified
// 16x16x32 B-operand layout). [verified R3/R4/R5: passed, absmax 2.4e-4]
// ---------------------------------------------------------------------------
__global__ __launch_bounds__(256) void wconvert(
    const float* __restrict__ w, uint4* __restrict__ wimg)
{
    const int s = blockIdx.x * 256 + threadIdx.x;     // 0..32767
    const int c    = s >> 10;
    const int r    = s & 1023;
    const int l    = r & 63;
    const int nt   = (r >> 6) & 1;
    const int kh   = (r >> 7) & 1;
    const int term = (r >> 8) & 1;
    const int eh   = (r >> 9) & 1;
    const int e = eh * 32 + nt * 16 + (l & 15);
    const int k = c * 64 + kh * 32 + (l >> 4) * 8;

    const float* src = w + (size_t)e * HIDDEN + k;
    union { _Float16 f[8]; uint4 u; } o;
    #pragma unroll
    for (int j = 0; j < 8; ++j) {
        const float v = src[j];
        const _Float16 h = (_Float16)v;
        o.f[j] = (term == 0) ? h : (_Float16)((v - (float)h) * 4096.f);
    }
    wimg[s] = o.u;
}

// ---------------------------------------------------------------------------
// Main (R6): BARRIER-FREE K-loop. 512 blocks x 256 thr; block = 32 tokens;
// wave wv = 32 tokens x 16 experts [16wv..16wv+16), all K. x rows in global
// memory already match the A-fragment layout (m=lane&15, k=(lane>>4)*8+j) ->
// direct global->VGPR fragment loads, no LDS staging, no __syncthreads in the
// loop. B frags from the wimg slice (coalesced, L2-resident). 2-term f16
// split (verified R3). Single barrier at the epilogue logits combine.
// ---------------------------------------------------------------------------
__global__ __launch_bounds__(256, 2) void router_main(
    const float* __restrict__ x, const uint4* __restrict__ wimg,
    float* __restrict__ out, float* __restrict__ zpartial)
{
    __shared__ float lg[MT * 66];        // logits [32][66] (pad 2)
    __shared__ float zred[4];

    const int tid  = threadIdx.x;
    const int wv   = __builtin_amdgcn_readfirstlane(tid >> 6);
    const int lane = tid & 63;
    const int eh   = wv >> 1;
    const int nt   = wv & 1;
    const int t0   = blockIdx.x * MT;

    // A-fragment addresses: lane element (m, k) = (lane&15, (lane>>4)*8 + j)
    const int am = lane & 15;
    const int ak = (lane >> 4) * 8;
    const float* aptr[2][2];             // [mt][jh]: 16B each, step adds 32 floats
    #pragma unroll
    for (int mt = 0; mt < 2; ++mt)
        #pragma unroll
        for (int jh = 0; jh < 2; ++jh)
            aptr[mt][jh] = x + (size_t)(t0 + 16 * mt + am) * HIDDEN + ak + 4 * jh;

    // B-fragment source: this wave's (eh,nt) slice; step s -> chunk s>>1, kh s&1
    const uint4* bptr = wimg + eh * 512 + nt * 64 + lane;   // + (s>>1)*1024 + (s&1)*128 + term*256

    f32x4 acc0[2], acc1[2];
    #pragma unroll
    for (int mt = 0; mt < 2; ++mt) { acc0[mt] = (f32x4)0.f; acc1[mt] = (f32x4)0.f; }

    // ---- software pipeline: prefetch step 0 ----
    float4 curA[2][2];  uint4 curB[2];
    #pragma unroll
    for (int mt = 0; mt < 2; ++mt)
        #pragma unroll
        for (int jh = 0; jh < 2; ++jh)
            curA[mt][jh] = *(const float4*)(aptr[mt][jh]);
    #pragma unroll
    for (int t = 0; t < 2; ++t)
        curB[t] = *(bptr + t * 256);

    #pragma unroll 2
    for (int s = 0; s < NSTEP; ++s) {
        // prefetch step s+1 (clamped -> branch-free; last iter re-reads s=63)
        const int sn = (s + 1 < NSTEP) ? s + 1 : NSTEP - 1;
        float4 nxtA[2][2];  uint4 nxtB[2];
        #pragma unroll
        for (int mt = 0; mt < 2; ++mt)
            #pragma unroll
            for (int jh = 0; jh < 2; ++jh)
                nxtA[mt][jh] = *(const float4*)(aptr[mt][jh] + sn * 32);
        #pragma unroll
        for (int t = 0; t < 2; ++t)
            nxtB[t] = *(bptr + (sn >> 1) * 1024 + (sn & 1) * 128 + t * 256);

        // convert curA -> Ah/Al fragments (2-term split, verified R3)
        f16x8 Ah[2], Al[2];
        #pragma unroll
        for (int mt = 0; mt < 2; ++mt) {
            union { _Float16 f[8]; f16x8 v; } hh, ll;
            #pragma unroll
            for (int j = 0; j < 8; ++j) {
                const float sv = (&curA[mt][j >> 2].x)[j & 3];
                const _Float16 h = (_Float16)sv;
                hh.f[j] = h;
                ll.f[j] = (_Float16)((sv - (float)h) * 4096.f);
            }
            Ah[mt] = hh.v;  Al[mt] = ll.v;
        }
        const f16x8 Bh = *(const f16x8*)&curB[0];
        const f16x8 Bl = *(const f16x8*)&curB[1];

        #pragma unroll
        for (int mt = 0; mt < 2; ++mt) {
            acc0[mt] = __builtin_amdgcn_mfma_f32_16x16x32_f16(Ah[mt], Bh, acc0[mt], 0, 0, 0);
            acc1[mt] = __builtin_amdgcn_mfma_f32_16x16x32_f16(Ah[mt], Bl, acc1[mt], 0, 0, 0);
            acc1[mt] = __builtin_amdgcn_mfma_f32_16x16x32_f16(Al[mt], Bh, acc1[mt], 0, 0, 0);
        }

        #pragma unroll
        for (int mt = 0; mt < 2; ++mt)
            #pragma unroll
            for (int jh = 0; jh < 2; ++jh)
                curA[mt][jh] = nxtA[mt][jh];
        curB[0] = nxtB[0];  curB[1] = nxtB[1];
    }

    // ---- epilogue: combine terms into LDS logits (single barrier) ----
    // C/D layout: col = lane&15 (expert offset), row = (lane>>4)*4 + r (token)
    #pragma unroll
    for (int mt = 0; mt < 2; ++mt)
        #pragma unroll
        for (int r = 0; r < 4; ++r) {
            const int tok = 16 * mt + (lane >> 4) * 4 + r;
            const int e   = 16 * wv + (lane & 15);
            lg[tok * 66 + e] = acc0[mt][r] + acc1[mt][r] * (1.f / 4096.f);
        }
    __syncthreads();

    // ---- routing (R1-verified math): wave handles 8 tokens, lane = expert ----
    float zsum = 0.f;
    for (int tt = 0; tt < 8; ++tt) {
        const int t = wv * 8 + tt;
        const float v = lg[t * 66 + lane];

        float bv = v; int bi = lane;
        #pragma unroll
        for (int s = 1; s < 64; s <<= 1) {
            const float ov = __shfl_xor(bv, s, 64);
            const int   oi = __shfl_xor(bi, s, 64);
            if (ov > bv || (ov == bv && oi < bi)) { bv = ov; bi = oi; }
        }
        const float max1 = bv; const int s1 = bi;

        const float e1 = expf(v - max1);
        const float sume = wave_sum64(e1);
        out[GATES_OFF + (size_t)(t0 + t) * NEXP + lane] = e1 / sume;
        const float lse = max1 + logf(sume);
        zsum += lse * lse;

        const bool mask1 = (max1 - v) > 0.02f * fmaxf(fabsf(v), max1);
        const float sum1 = wave_sum64(mask1 ? 0.f : e1);

        float bv2 = (lane == s1) ? -INFINITY : v; int bi2 = lane;
        #pragma unroll
        for (int s = 1; s < 64; s <<= 1) {
            const float ov = __shfl_xor(bv2, s, 64);
            const int   oi = __shfl_xor(bi2, s, 64);
            if (ov > bv2 || (ov == bv2 && oi < bi2)) { bv2 = ov; bi2 = oi; }
        }
        const float max2 = bv2; const int s2 = bi2;

        const bool mask2 = (max2 - v) > 0.02f * fmaxf(fabsf(v), max2);
        const float p2v = (mask2 || lane == s1) ? 0.f : expf(v - max2);
        const float sum2 = wave_sum64(p2v);

        if (lane == 0) {
            const size_t trow = (size_t)(t0 + t) * 2;
            out[trow + 0] = 1.f / sum1;
            out[trow + 1] = 1.f / sum2;
            out[SEL_OFF + trow + 0] = (float)s1;
            out[SEL_OFF + trow + 1] = (float)s2;
        }
    }

    if (lane == 0) zred[wv] = zsum;
    __syncthreads();
    if (tid == 0)
        zpartial[blockIdx.x] = zred[0] + zred[1] + zred[2] + zred[3];
}

__global__ __launch_bounds__(256) void zfinal(
    const float* __restrict__ zpartial, float* __restrict__ out)
{
    const int tid = threadIdx.x;                 // 512 partials, 256 threads
    float v = zpartial[tid] + zpartial[tid + 256];
    v = wave_sum64(v);
    __shared__ float red[4];
    if ((tid & 63) == 0) red[tid >> 6] = v;
    __syncthreads();
    if (tid == 0) {
        const float tot = red[0] + red[1] + red[2] + red[3];
        out[Z_OFF] = 0.001f * (tot / (float)TOKENS);
    }
}

extern "C" void kernel_launch(void* const* d_in, const int* in_sizes, int n_in,
                              void* d_out, int out_size, void* d_ws, size_t ws_size,
                              hipStream_t stream) {
    const float* x = (const float*)d_in[0];   // [16384, 2048] fp32
    const float* w = (const float*)d_in[1];   // [64, 2048] fp32
    float* out = (float*)d_out;               // mult(32768) | gates(1048576) | sel(32768) | z(1)

    uint4* wimg     = (uint4*)d_ws;                               // 512 KB
    float* zpartial = (float*)((char*)d_ws + WIMG_BYTES);         // 512 floats

    wconvert<<<128, 256, 0, stream>>>(w, wimg);
    router_main<<<NBLK, 256, 0, stream>>>(x, wimg, out, zpartial);
    zfinal<<<1, 256, 0, stream>>>(zpartial, out);
}